// Round 5
// baseline (2565.283 us; speedup 1.0000x reference)
//
#include <hip/hip_runtime.h>
#include <hip/hip_cooperative_groups.h>

namespace cg = cooperative_groups;

typedef _Float16 f16;
typedef f16 f16x8 __attribute__((ext_vector_type(8)));
typedef f16 f16x4 __attribute__((ext_vector_type(4)));
typedef f16 f16x2 __attribute__((ext_vector_type(2)));
typedef float f32x4 __attribute__((ext_vector_type(4)));

#define B_ 64
#define C_ 512
#define X2D_ELEMS ((size_t)134217728)  // 64*512*64*64
#define CHAIN_PITCH 1104               // cols per b in chain [b][col][512]

// (i,j) -> chain column, or -1 if not on any written diagonal
__device__ __forceinline__ int col_of(int i, int j) {
    const int d = j - i;
    if (d < 0) return -1;
    if (d <= 15) return 64 * d - (d * (d - 1)) / 2 + i;
    if (d >= 17 && d <= 31 && (d & 1) && !(i & 1)) {
        const int v = (d - 17) >> 1;
        return 904 + 24 * v - (v * (v - 1)) / 2 + (i >> 1);
    }
    if (d >= 35 && !((d - 35) & 3) && !(i & 3)) {
        const int v = (d - 35) >> 2;
        return 1068 + 8 * v - (v * (v - 1)) / 2 + (i >> 2);
    }
    return -1;
}

// ---------------------------------------------------------------------------
// one conv GEMM unit: 64 co x G batches. B staged once in LDS (chunk-XOR
// swizzle), barrier-free K loop, f16 weights from global (L2-resident).
// K ordering: k = t*512 + ci; works for K=512 (t always 0) and K=1024.
// ---------------------------------------------------------------------------
__device__ __forceinline__
void conv_unit(f16* S, const f16* __restrict__ xin, int in_pitch, int cb_in,
               const f16* __restrict__ Wl, const float* __restrict__ bias,
               f16* __restrict__ chain, int cb_out,
               int Lin, int Lout, int G, int K, int b0, int m0)
{
    const int tid = threadIdx.x, lane = tid & 63, wv = tid >> 6;
    const int rows = G * Lin;
    for (int r = wv; r < rows; r += 4) {
        const int g = r / Lin, l = r - g * Lin;
        const f16* src = xin + (((size_t)(b0 + g) * in_pitch + cb_in + l) << 9);
        const f16x8 v = *(const f16x8*)(src + (lane << 3));
        *(f16x8*)&S[(r << 9) + ((lane ^ (r & 7)) << 3)] = v;
    }
    int vg[4], vl[4], row0[4]; bool val[4];
    #pragma unroll
    for (int nf = 0; nf < 4; nf++) {
        const int v = nf * 16 + (lane & 15);
        vg[nf] = v / Lout; vl[nf] = v - vg[nf] * Lout;
        val[nf] = vg[nf] < G;
        row0[nf] = val[nf] ? vg[nf] * Lin + vl[nf] : 0;
    }
    const int kg = lane >> 4;
    const f16* wp = Wl + (size_t)(m0 + wv * 16 + (lane & 15)) * K + (kg << 3);
    __syncthreads();
    f32x4 acc[4] = {};
    #pragma unroll 4
    for (int k0 = 0; k0 < K; k0 += 32) {
        const f16x8 af = *(const f16x8*)(wp + k0);
        const int t = (k0 >= 512) ? 1 : 0;
        const int cchunk = ((k0 & 511) >> 3) + kg;
        #pragma unroll
        for (int nf = 0; nf < 4; nf++) {
            const int r = row0[nf] + t;
            const f16x8 bf = *(const f16x8*)&S[(r << 9) + ((cchunk ^ (r & 7)) << 3)];
            acc[nf] = __builtin_amdgcn_mfma_f32_16x16x32_f16(af, bf, acc[nf], 0, 0, 0);
        }
    }
    const int co0 = m0 + wv * 16 + ((lane >> 4) << 2);
    const float4 bb = *(const float4*)&bias[co0];
    #pragma unroll
    for (int nf = 0; nf < 4; nf++) {
        if (!val[nf]) continue;
        f16x4 h;
        #pragma unroll
        for (int j = 0; j < 4; j++)
            h[j] = (f16)fmaxf(acc[nf][j] + ((const float*)&bb)[j], 0.0f);
        *(f16x4*)&chain[(((size_t)(b0 + vg[nf]) * CHAIN_PITCH + cb_out + vl[nf]) << 9) + co0] = h;
    }
}

// one assemble unit (i, b): stage 64 j-rows (zero for invalid), coalesced
// x2d write via swizzled LDS gather
__device__ __forceinline__
void assemble_unit(f16* S, const f16* __restrict__ chain, float* __restrict__ x2d,
                   int i, int b)
{
    const int tid = threadIdx.x, lane = tid & 63, wv = tid >> 6;
    for (int j = wv; j < 64; j += 4) {
        const int col = col_of(i, j);
        f16x8 v = {0, 0, 0, 0, 0, 0, 0, 0};
        if (col >= 0)
            v = *(const f16x8*)(chain + (((size_t)b * CHAIN_PITCH + col) << 9) + (lane << 3));
        *(f16x8*)&S[(j << 9) + ((lane ^ (j & 7)) << 3)] = v;
    }
    __syncthreads();
    const int jq = tid & 15, c0 = tid >> 4;
    float* dst0 = x2d + (((size_t)b * C_) << 12) + (i << 6) + (jq << 2);
    for (int ct = 0; ct < 32; ct++) {
        const int c = c0 + (ct << 4);
        const int cj = c >> 3;
        float4 o;
        #pragma unroll
        for (int jj = 0; jj < 4; jj++) {
            const int j = (jq << 2) + jj;
            ((float*)&o)[jj] = (float)S[(j << 9) + ((cj ^ (j & 7)) << 3) + (c & 7)];
        }
        *(float4*)(dst0 + ((size_t)c << 12)) = o;
    }
}

// one x-transpose unit: fp32 [b][512][64] slab s -> f16 [b][l][512]
__device__ __forceinline__
void xtrans_unit(f16* S, const float* __restrict__ x, f16* __restrict__ xT,
                 int s, int b)
{
    f16 (*t)[20] = (f16 (*)[20])S;
    const int tid = threadIdx.x;
    const int ci = tid >> 4, l0 = (tid & 15) << 2;
    const float4 v = *(const float4*)&x[(((size_t)b * C_ + s * 16 + ci) << 6) + l0];
    t[l0 + 0][ci] = (f16)v.x; t[l0 + 1][ci] = (f16)v.y;
    t[l0 + 2][ci] = (f16)v.z; t[l0 + 3][ci] = (f16)v.w;
    __syncthreads();
    const int l = tid >> 2, q = tid & 3;
    const f16x4 o = *(const f16x4*)&t[l][q << 2];
    *(f16x4*)&xT[((((size_t)b << 6) + l) << 9) + (s << 4) + (q << 2)] = o;
}

// weight convert/reorder: one element of [co][t*512+ci] from w1/w2
__device__ __forceinline__
void wprep_one(unsigned idx, const float* __restrict__ w1,
               const float* __restrict__ w2, f16* __restrict__ Wf)
{
    if (idx < 262144u) {
        Wf[idx] = (f16)w1[idx];
    } else {
        const unsigned r = idx - 262144u;
        const int k2 = r >> 18;
        const unsigned rem = r & 262143u;
        const int co = rem >> 9, ci = rem & 511;
        const float2 v = *(const float2*)&w2[((((size_t)k2 << 9) + co) << 10) + (ci << 1)];
        f16* base = Wf + 262144 + ((size_t)k2 << 19) + ((size_t)co << 10);
        base[ci] = (f16)v.x;
        base[512 + ci] = (f16)v.y;
    }
}

// ---------------------------------------------------------------------------
// THE persistent cooperative kernel: prep -> 32 layers (grid.sync each) ->
// assemble. All unit loops are grid-stride, so any grid size is correct.
// ---------------------------------------------------------------------------
__global__ __launch_bounds__(256, 2)
void persist(const float* __restrict__ x, const float* __restrict__ w1,
             const float* __restrict__ b1, const float* __restrict__ w2,
             const float* __restrict__ b2, f16* __restrict__ chain,
             f16* __restrict__ Wf, f16* __restrict__ xT,
             float* __restrict__ x2d, float* __restrict__ maskp)
{
    __shared__ __align__(16) f16 S[64 * 512];   // 64 KB
    cg::grid_group gg = cg::this_grid();
    const int tid = threadIdx.x, bid = blockIdx.x, nB = gridDim.x;
    const int gid = bid * 256 + tid, nT = nB * 256;

    // ---- phase 0: mask + weight prep + x transpose
    if (gid < 4096) maskp[gid] = (col_of(gid >> 6, gid & 63) >= 0) ? 1.0f : 0.0f;
    for (unsigned idx = gid; idx < 30u * 262144u; idx += nT)
        wprep_one(idx, w1, w2, Wf);
    for (int u = bid; u < 2048; u += nB) {
        __syncthreads();
        xtrans_unit(S, x, xT, u & 31, u >> 5);
    }
    __threadfence();
    gg.sync();

    // ---- 32 layers
    int L = 64, k2 = 0, cb = 0, prev = 0;
    for (int level = 0; level < 3; level++) {
        const int cnt = (level == 0) ? 16 : 8;
        for (int order = 0; order < cnt; order++) {
            if (level == 0 && order == 0) {
                for (int u = bid; u < 512; u += nB) {
                    __syncthreads();
                    conv_unit(S, xT, 64, 0, Wf, b1, chain, cb,
                              64, 64, 1, 512, u & 63, (u >> 6) << 6);
                }
            } else if (level > 0 && order == 0) {
                const int Lp = (L - 3) / 2 + 1;
                const int tot = B_ * Lp * 256;
                for (int t = gid; t < tot; t += nT) {
                    const int b = t / (Lp * 256);
                    const int r = t - b * (Lp * 256);
                    const int l = r >> 8, cp = r & 255;
                    const f16* sp = chain + (((size_t)b * CHAIN_PITCH + prev + 2 * l) << 9) + 2 * cp;
                    f16x2 o;
                    o[0] = (f16)fmaxf(fmaxf(fmaxf((float)sp[0], (float)sp[512]), (float)sp[1024]), 0.0f);
                    o[1] = (f16)fmaxf(fmaxf(fmaxf((float)sp[1], (float)sp[513]), (float)sp[1025]), 0.0f);
                    *(f16x2*)&chain[(((size_t)b * CHAIN_PITCH + cb + l) << 9) + 2 * cp] = o;
                }
                L = Lp;
            } else {
                const int Lout = L - 1;
                int G = 1;
                while ((G * 2) * Lout <= 64 && (G * 2) * L <= 64) G *= 2;
                const int ubg = 64 / G, units = ubg * 8;
                const f16* Wl = Wf + 262144 + (size_t)k2 * 524288;
                const float* bl = b2 + (size_t)k2 * C_;
                for (int u = bid; u < units; u += nB) {
                    __syncthreads();
                    conv_unit(S, chain, CHAIN_PITCH, prev, Wl, bl, chain, cb,
                              L, Lout, G, 1024, (u % ubg) * G, (u / ubg) << 6);
                }
                k2++; L = Lout;
            }
            prev = cb; cb += L;
            __threadfence();
            gg.sync();
        }
    }

    // ---- assemble x2d (overwrites the Wf/xT scratch region too)
    for (int u = bid; u < 4096; u += nB) {
        __syncthreads();
        assemble_unit(S, chain, x2d, u & 63, u >> 6);
    }
}

// ---------------------------------------------------------------------------
// fallback wrappers (R4-proven multi-kernel path), used only if the
// cooperative launch is rejected
// ---------------------------------------------------------------------------
__global__ __launch_bounds__(256, 2)
void conv_k(const f16* __restrict__ xin, int in_pitch, int cb_in,
            const f16* __restrict__ Wl, const float* __restrict__ bias,
            f16* __restrict__ chain, int cb_out, int Lin, int Lout, int G, int K)
{
    __shared__ __align__(16) f16 S[64 * 512];
    conv_unit(S, xin, in_pitch, cb_in, Wl, bias, chain, cb_out,
              Lin, Lout, G, K, blockIdx.x * G, blockIdx.y << 6);
}

__global__ void maxpool_kf(f16* __restrict__ chain, int cb_in, int cb_out)
{
    const int l = blockIdx.x, b = blockIdx.y, tid = threadIdx.x;
    const f16* s = chain + (((size_t)b * CHAIN_PITCH + cb_in + 2 * l) << 9) + 2 * tid;
    f16x2 o;
    o[0] = (f16)fmaxf(fmaxf(fmaxf((float)s[0], (float)s[512]), (float)s[1024]), 0.0f);
    o[1] = (f16)fmaxf(fmaxf(fmaxf((float)s[1], (float)s[513]), (float)s[1025]), 0.0f);
    *(f16x2*)&chain[(((size_t)b * CHAIN_PITCH + cb_out + l) << 9) + 2 * tid] = o;
}

__global__ void mask_k(float* __restrict__ mout)
{
    const int t = blockIdx.x * 256 + threadIdx.x;
    mout[t] = (col_of(t >> 6, t & 63) >= 0) ? 1.0f : 0.0f;
}

__global__ void wprep_k(const float* __restrict__ w1, const float* __restrict__ w2,
                        f16* __restrict__ Wf)
{
    wprep_one((unsigned)(blockIdx.x * 256 + threadIdx.x), w1, w2, Wf);
}

__global__ __launch_bounds__(256)
void xtrans_k(const float* __restrict__ x, f16* __restrict__ xT)
{
    __shared__ __align__(16) f16 S[64 * 20];
    xtrans_unit(S, x, xT, blockIdx.x, blockIdx.y);
}

__global__ __launch_bounds__(256)
void assemble_k(const f16* __restrict__ chain, float* __restrict__ x2d)
{
    __shared__ __align__(16) f16 S[64 * 512];
    assemble_unit(S, chain, x2d, blockIdx.x, blockIdx.y);
}

extern "C" void kernel_launch(void* const* d_in, const int* in_sizes, int n_in,
                              void* d_out, int out_size, void* d_ws, size_t ws_size,
                              hipStream_t stream)
{
    const float* x  = (const float*)d_in[0];
    const float* w1 = (const float*)d_in[1];
    const float* b1 = (const float*)d_in[2];
    const float* w2 = (const float*)d_in[3];
    const float* b2 = (const float*)d_in[4];
    float* x2d   = (float*)d_out;
    float* maskp = x2d + X2D_ELEMS;

    // chain in d_ws (72.3 MB); f16 weights + xT in the d_out scratch region
    // (35 MB), overwritten by the assemble phase after weights are dead.
    f16* chain = (f16*)d_ws;
    f16* Wf = (f16*)x2d;
    f16* xT = Wf + 262144 + (size_t)29 * 524288;

    // grid size: 2 blocks/CU if the runtime agrees (LDS-limited), else 1/CU
    int maxB = 0;
    hipError_t oe = hipOccupancyMaxActiveBlocksPerMultiprocessor(
        &maxB, (const void*)persist, 256, 0);
    const int nB = (oe == hipSuccess && maxB >= 2) ? 512 : 256;

    void* args[] = {(void*)&x, (void*)&w1, (void*)&b1, (void*)&w2, (void*)&b2,
                    (void*)&chain, (void*)&Wf, (void*)&xT, (void*)&x2d, (void*)&maskp};
    hipError_t le = hipLaunchCooperativeKernel((const void*)persist, dim3(nB),
                                               dim3(256), args, 0, stream);
    if (le == hipSuccess) return;

    // ---- fallback: R4-proven multi-kernel path
    mask_k<<<16, 256, 0, stream>>>(maskp);
    wprep_k<<<(30 * 262144) / 256, 256, 0, stream>>>(w1, w2, Wf);
    xtrans_k<<<dim3(32, B_), 256, 0, stream>>>(x, xT);

    const int counts[3] = {16, 8, 8};
    int L = 64, k2 = 0, cb = 0, prev = 0;
    for (int level = 0; level < 3; level++) {
        for (int order = 0; order < counts[level]; order++) {
            if (level == 0 && order == 0) {
                conv_k<<<dim3(64, 8), 256, 0, stream>>>(
                    xT, 64, 0, Wf, b1, chain, cb, 64, 64, 1, 512);
            } else if (level > 0 && order == 0) {
                const int Lp = (L - 3) / 2 + 1;
                maxpool_kf<<<dim3(Lp, B_), 256, 0, stream>>>(chain, prev, cb);
                L = Lp;
            } else {
                const int Lout = L - 1;
                int G = 1;
                while ((G * 2) * Lout <= 64 && (G * 2) * L <= 64) G *= 2;
                conv_k<<<dim3(64 / G, 8), 256, 0, stream>>>(
                    chain, CHAIN_PITCH, prev, Wf + 262144 + (size_t)k2 * 524288,
                    b2 + (size_t)k2 * C_, chain, cb, L, Lout, G, 1024);
                k2++; L = Lout;
            }
            prev = cb; cb += L;
        }
        L = L;
    }
    assemble_k<<<dim3(64, B_), 256, 0, stream>>>(chain, x2d);
}

// Round 6
// 1216.120 us; speedup vs baseline: 2.1094x; 2.1094x over previous
//
#include <hip/hip_runtime.h>

typedef _Float16 f16;
typedef f16 f16x8 __attribute__((ext_vector_type(8)));
typedef f16 f16x4 __attribute__((ext_vector_type(4)));
typedef float f32x4 __attribute__((ext_vector_type(4)));

#define B_ 64
#define C_ 512
#define X2D_ELEMS ((size_t)134217728)  // 64*512*64*64
#define CHAIN_PITCH 1104               // chain: [b][col][512] f16

// (i,j) -> chain column, or -1 if not on any written diagonal
__device__ __forceinline__ int col_of(int i, int j) {
    const int d = j - i;
    if (d < 0) return -1;
    if (d <= 15) return 64 * d - (d * (d - 1)) / 2 + i;
    if (d >= 17 && d <= 31 && (d & 1) && !(i & 1)) {
        const int v = (d - 17) >> 1;
        return 904 + 24 * v - (v * (v - 1)) / 2 + (i >> 1);
    }
    if (d >= 35 && !((d - 35) & 3) && !(i & 3)) {
        const int v = (d - 35) >> 2;
        return 1068 + 8 * v - (v * (v - 1)) / 2 + (i >> 2);
    }
    return -1;
}

// ---------------------------------------------------------------------------
// one conv layer, fully in-LDS: Scur [Lin rows][512 ci, chunk-XOR swizzled]
// -> Snxt [Lout rows][512 co, swizzled] + chain global write.
// 4 waves, each 128 co x (NF*16) cols. A (f16 weights [co][t*512+ci]) from
// global (L2-shared across the 64 b-blocks), explicit double-buffer prefetch.
// All fragment arrays statically indexed (templated NF).
// ---------------------------------------------------------------------------
template<int K, int NF, int TAPS>
__device__ __forceinline__
void conv_step(const f16* Scur, f16* Snxt,
               const f16* __restrict__ wl, const float* __restrict__ bias,
               f16* __restrict__ chout, int Lin, int Lout)
{
    const int tid = threadIdx.x, lane = tid & 63, w = tid >> 6;
    const int colq = lane & 15, kg = lane >> 4;
    const f16* wp = wl + (size_t)(w * 128 + colq) * K + (kg << 3);

    int row[NF];
    #pragma unroll
    for (int nf = 0; nf < NF; nf++) {
        int c = nf * 16 + colq;
        if (TAPS == 2 && c > Lin - 2) c = Lin - 2;   // clamp padded cols (masked later)
        row[nf] = c;
    }

    f32x4 acc[8][NF] = {};
    f16x8 afA[8], afB[8];
    #pragma unroll
    for (int m = 0; m < 8; m++) afA[m] = *(const f16x8*)(wp + (m << 4) * K);

    for (int k0 = 0; k0 < K; k0 += 64) {
        #pragma unroll
        for (int m = 0; m < 8; m++)
            afB[m] = *(const f16x8*)(wp + (m << 4) * K + k0 + 32);
        {   // sub-step A: k = k0
            const int t = (TAPS == 2 && k0 >= 512) ? 1 : 0;
            const int cch = ((k0 & 511) >> 3) + kg;
            f16x8 bf[NF];
            #pragma unroll
            for (int nf = 0; nf < NF; nf++) {
                const int r = row[nf] + t;
                bf[nf] = *(const f16x8*)&Scur[(r << 9) + ((cch ^ (r & 7)) << 3)];
            }
            #pragma unroll
            for (int m = 0; m < 8; m++)
                #pragma unroll
                for (int nf = 0; nf < NF; nf++)
                    acc[m][nf] = __builtin_amdgcn_mfma_f32_16x16x32_f16(
                        afA[m], bf[nf], acc[m][nf], 0, 0, 0);
        }
        if (k0 + 64 < K) {
            #pragma unroll
            for (int m = 0; m < 8; m++)
                afA[m] = *(const f16x8*)(wp + (m << 4) * K + k0 + 64);
        }
        {   // sub-step B: k = k0 + 32
            const int k1 = k0 + 32;
            const int t = (TAPS == 2 && k1 >= 512) ? 1 : 0;
            const int cch = ((k1 & 511) >> 3) + kg;
            f16x8 bf[NF];
            #pragma unroll
            for (int nf = 0; nf < NF; nf++) {
                const int r = row[nf] + t;
                bf[nf] = *(const f16x8*)&Scur[(r << 9) + ((cch ^ (r & 7)) << 3)];
            }
            #pragma unroll
            for (int m = 0; m < 8; m++)
                #pragma unroll
                for (int nf = 0; nf < NF; nf++)
                    acc[m][nf] = __builtin_amdgcn_mfma_f32_16x16x32_f16(
                        afB[m], bf[nf], acc[m][nf], 0, 0, 0);
        }
    }

    // epilogue: bias+relu+cvt; write Snxt (B-layout, swizzled) + chain global
    #pragma unroll
    for (int m = 0; m < 8; m++) {
        const int co = w * 128 + (m << 4) + (kg << 2);
        const float4 bb = *(const float4*)&bias[co];
        #pragma unroll
        for (int nf = 0; nf < NF; nf++) {
            const int col = nf * 16 + colq;
            if (col < Lout) {
                f16x4 h;
                #pragma unroll
                for (int j = 0; j < 4; j++)
                    h[j] = (f16)fmaxf(acc[m][nf][j] + ((const float*)&bb)[j], 0.0f);
                *(f16x4*)&Snxt[(col << 9) + ((((co >> 3) ^ (col & 7)) << 3) + (co & 7))] = h;
                *(f16x4*)&chout[((size_t)col << 9) + co] = h;
            }
        }
    }
}

// MaxPool1d(k=3,s=2) in-LDS + chain write (inputs already >= 0, relu no-op)
__device__ __forceinline__
void pool_step(const f16* Scur, f16* Snxt, f16* __restrict__ chout, int Lp)
{
    for (int u = threadIdx.x; u < Lp * 64; u += 256) {
        const int l = u >> 6, c8 = u & 63;
        const int r0 = 2 * l, r1 = r0 + 1, r2 = r0 + 2;
        const f16x8 a = *(const f16x8*)&Scur[(r0 << 9) + ((c8 ^ (r0 & 7)) << 3)];
        const f16x8 d = *(const f16x8*)&Scur[(r1 << 9) + ((c8 ^ (r1 & 7)) << 3)];
        const f16x8 e = *(const f16x8*)&Scur[(r2 << 9) + ((c8 ^ (r2 & 7)) << 3)];
        f16x8 o;
        #pragma unroll
        for (int j = 0; j < 8; j++)
            o[j] = (f16)fmaxf(fmaxf((float)a[j], (float)d[j]), fmaxf((float)e[j], 0.0f));
        *(f16x8*)&Snxt[(l << 9) + ((c8 ^ (l & 7)) << 3)] = o;
        *(f16x8*)&chout[((size_t)l << 9) + (c8 << 3)] = o;
    }
}

// ---------------------------------------------------------------------------
// THE chain kernel: one block per batch b; all 32 layers with activations
// resident in LDS (2 x 64 KB double buffer); __syncthreads between layers.
// No grid-wide sync anywhere — the chain is batch-independent.
// ---------------------------------------------------------------------------
__global__ __launch_bounds__(256, 1)
void chain_all(const float* __restrict__ x, const f16* __restrict__ Wf,
               const float* __restrict__ b1, const float* __restrict__ b2,
               f16* __restrict__ chain)
{
    __shared__ __align__(16) f16 S[2][64 * 512];   // 128 KB
    const int b = blockIdx.x, tid = threadIdx.x;
    f16* chb = chain + (((size_t)b * CHAIN_PITCH) << 9);

    // stage x[b] fp32 [512 ci][64 l] -> S[0] f16 [l][ci swizzled]
    for (int p = 0; p < 32; p++) {
        const int ci = p * 16 + (tid >> 4), l0 = (tid & 15) << 2;
        const float4 v = *(const float4*)&x[(((size_t)b * C_ + ci) << 6) + l0];
        #pragma unroll
        for (int j = 0; j < 4; j++) {
            const int r = l0 + j;
            S[0][(r << 9) + (((ci >> 3) ^ (r & 7)) << 3) + (ci & 7)] =
                (f16)((const float*)&v)[j];
        }
    }
    __syncthreads();

    int cur = 0, cb = 0, L = 64, k2 = 0;

    // layer 0: k=1 conv, K=512
    conv_step<512, 4, 1>(S[0], S[1], Wf, b1, chb, 64, 64);
    __syncthreads();
    cur = 1; cb = 64;

    // level 0: 15 k=2 convs (64 -> 49)
    for (int i = 0; i < 15; i++) {
        const int Lout = L - 1;
        conv_step<1024, 4, 2>(S[cur], S[cur ^ 1], Wf + 262144 + (size_t)k2 * 524288,
                              b2 + k2 * C_, chb + ((size_t)cb << 9), L, Lout);
        __syncthreads();
        cur ^= 1; cb += Lout; L = Lout; k2++;
    }
    // pool -> 24, then 7 convs (24 -> 17)
    {
        const int Lp = (L - 3) / 2 + 1;
        pool_step(S[cur], S[cur ^ 1], chb + ((size_t)cb << 9), Lp);
        __syncthreads();
        cur ^= 1; cb += Lp; L = Lp;
    }
    for (int i = 0; i < 7; i++) {
        const int Lout = L - 1;
        conv_step<1024, 2, 2>(S[cur], S[cur ^ 1], Wf + 262144 + (size_t)k2 * 524288,
                              b2 + k2 * C_, chb + ((size_t)cb << 9), L, Lout);
        __syncthreads();
        cur ^= 1; cb += Lout; L = Lout; k2++;
    }
    // pool -> 8, then 7 convs (8 -> 1)
    {
        const int Lp = (L - 3) / 2 + 1;
        pool_step(S[cur], S[cur ^ 1], chb + ((size_t)cb << 9), Lp);
        __syncthreads();
        cur ^= 1; cb += Lp; L = Lp;
    }
    for (int i = 0; i < 7; i++) {
        const int Lout = L - 1;
        conv_step<1024, 1, 2>(S[cur], S[cur ^ 1], Wf + 262144 + (size_t)k2 * 524288,
                              b2 + k2 * C_, chb + ((size_t)cb << 9), L, Lout);
        __syncthreads();
        cur ^= 1; cb += Lout; L = Lout; k2++;
    }
}

// prep: mask + weights fp32 -> f16 reordered to [co][t*512+ci]
__global__ void prep_k(const float* __restrict__ w1, const float* __restrict__ w2,
                       f16* __restrict__ Wf, float* __restrict__ maskp)
{
    const unsigned idx = blockIdx.x * 256 + threadIdx.x;
    if (idx < 4096u)
        maskp[idx] = (col_of(idx >> 6, idx & 63) >= 0) ? 1.0f : 0.0f;
    if (idx < 262144u) {
        Wf[idx] = (f16)w1[idx];
    } else if (idx < 30u * 262144u) {
        const unsigned r = idx - 262144u;
        const int k2 = r >> 18;
        const unsigned rem = r & 262143u;
        const int co = rem >> 9, ci = rem & 511;
        const float2 v = *(const float2*)&w2[((((size_t)k2 << 9) + co) << 10) + (ci << 1)];
        f16* base = Wf + 262144 + ((size_t)k2 << 19) + ((size_t)co << 10);
        base[ci] = (f16)v.x;
        base[512 + ci] = (f16)v.y;
    }
}

// assemble (R4-proven): block=(i, b); stage 64 j-rows swizzled; coalesced write
__global__ __launch_bounds__(256)
void assemble_k(const f16* __restrict__ chain, float* __restrict__ x2d)
{
    __shared__ __align__(16) f16 S[64 * 512];
    const int tid = threadIdx.x, lane = tid & 63, wv = tid >> 6;
    const int i = blockIdx.x, b = blockIdx.y;

    for (int j = wv; j < 64; j += 4) {
        const int col = col_of(i, j);
        f16x8 v = {0, 0, 0, 0, 0, 0, 0, 0};
        if (col >= 0)
            v = *(const f16x8*)(chain + (((size_t)b * CHAIN_PITCH + col) << 9) + (lane << 3));
        *(f16x8*)&S[(j << 9) + ((lane ^ (j & 7)) << 3)] = v;
    }
    __syncthreads();
    const int jq = tid & 15, c0 = tid >> 4;
    float* dst0 = x2d + (((size_t)b * C_) << 12) + (i << 6) + (jq << 2);
    for (int ct = 0; ct < 32; ct++) {
        const int c = c0 + (ct << 4);
        const int cj = c >> 3;
        float4 o;
        #pragma unroll
        for (int jj = 0; jj < 4; jj++) {
            const int j = (jq << 2) + jj;
            ((float*)&o)[jj] = (float)S[(j << 9) + ((cj ^ (j & 7)) << 3) + (c & 7)];
        }
        *(float4*)(dst0 + ((size_t)c << 12)) = o;
    }
}

extern "C" void kernel_launch(void* const* d_in, const int* in_sizes, int n_in,
                              void* d_out, int out_size, void* d_ws, size_t ws_size,
                              hipStream_t stream)
{
    const float* x  = (const float*)d_in[0];
    const float* w1 = (const float*)d_in[1];
    const float* b1 = (const float*)d_in[2];
    const float* w2 = (const float*)d_in[3];
    const float* b2 = (const float*)d_in[4];
    float* x2d   = (float*)d_out;
    float* maskp = x2d + X2D_ELEMS;

    // chain (72.3 MB) in d_ws; f16 weights (31 MB) in the x2d region —
    // fully overwritten by assemble_k after the chain is done.
    f16* chain = (f16*)d_ws;
    f16* Wf = (f16*)x2d;

    prep_k<<<(30 * 262144) / 256, 256, 0, stream>>>(w1, w2, Wf, maskp);
    chain_all<<<B_, 256, 0, stream>>>(x, Wf, b1, b2, chain);
    assemble_k<<<dim3(64, B_), 256, 0, stream>>>(chain, x2d);
}